// Round 1
// baseline (48.438 us; speedup 1.0000x reference)
//
#include <hip/hip_runtime.h>
#include <math.h>

#define NTHREADS 256
#define NF4      25        // float4 per LDS row (100 floats, 98 valid + 2 pad)
#define LDS_C    100
#define REG_R    98        // region rows = 64 + 34

__device__ __forceinline__ float4 f4max(const float4 a, const float4 b) {
    return make_float4(fmaxf(a.x, b.x), fmaxf(a.y, b.y),
                       fmaxf(a.z, b.z), fmaxf(a.w, b.w));
}

// One vertical doubling step: DST[r][*] = max(SRC[r][*], SRC[r+D][*]) for r < ROWS
#define VSTEP(SRC, DST, ROWS, D)                                              \
    for (int t = tid; t < (ROWS) * NF4; t += NTHREADS) {                      \
        const int r = t / NF4, j = t - r * NF4;                               \
        DST[r * NF4 + j] = f4max(SRC[r * NF4 + j], SRC[(r + (D)) * NF4 + j]); \
    }                                                                         \
    __syncthreads();

__global__ __launch_bounds__(NTHREADS, 2)
void dark_main(const float* __restrict__ x, float* __restrict__ part) {
    __shared__ float4 A4[REG_R * NF4];   // 39200 B
    __shared__ float4 B4[REG_R * NF4];   // 39200 B  (total 78.4 KB -> 2 blocks/CU)

    const int tid = threadIdx.x;
    const int bid = blockIdx.x;

    // XCD-aware swizzle: XCD k (bid%8) gets contiguous tile range [k*128,(k+1)*128)
    // = batches 2k,2k+1 -> each XCD L2 only touches ~6.3 MB unique.
    const int swz = (bid & 7) * 128 + (bid >> 3);
    const int b  = swz >> 6;          // 64 tiles per batch
    const int ty = (swz >> 3) & 7;
    const int tx = swz & 7;
    const int h0 = ty * 64 - 17;
    const int w0 = tx * 64 - 17;
    const float* xb = x + (size_t)b * (3u * 512u * 512u);

    // ---- load region: y = 1 - min_c(x), OOB/pad cols = -inf ----
    float* Af = (float*)A4;
    for (int t = tid; t < REG_R * LDS_C; t += NTHREADS) {
        const int r = t / LDS_C;
        const int c = t - r * LDS_C;
        float v = -INFINITY;
        const int gh = h0 + r, gw = w0 + c;
        if (c < 98 && (unsigned)gh < 512u && (unsigned)gw < 512u) {
            const float* p = xb + gh * 512 + gw;
            const float m = fminf(p[0], fminf(p[262144], p[524288]));
            v = 1.0f - m;
        }
        Af[t] = v;
    }
    __syncthreads();

    // ---- vertical sliding max (window 35) via doubling, ping-pong A<->B ----
    VSTEP(A4, B4, 97, 1)    // w=2
    VSTEP(B4, A4, 95, 2)    // w=4
    VSTEP(A4, B4, 91, 4)    // w=8
    VSTEP(B4, A4, 83, 8)    // w=16
    VSTEP(A4, B4, 67, 16)   // w=32
    VSTEP(B4, A4, 64, 3)    // w=35 : A rows 0..63 = vertical max, cols 0..97

    // ---- horizontal sliding max (window 35) in registers + partial sum ----
    float s = 0.0f;
    {
        const int r = tid >> 2;                 // 0..63
        const int j = tid & 3;                  // 16-col chunk
        const float4* Arow = A4 + r * NF4 + 4 * j;
        float v[52];
        #pragma unroll
        for (int i = 0; i < 13; ++i) {
            const float4 q = Arow[i];
            v[4*i] = q.x; v[4*i+1] = q.y; v[4*i+2] = q.z; v[4*i+3] = q.w;
        }
        // in-place doubling (ascending i is safe: only indices < i modified)
        #pragma unroll
        for (int i = 0; i <= 48; ++i) v[i] = fmaxf(v[i], v[i + 1]);
        #pragma unroll
        for (int i = 0; i <= 46; ++i) v[i] = fmaxf(v[i], v[i + 2]);
        #pragma unroll
        for (int i = 0; i <= 42; ++i) v[i] = fmaxf(v[i], v[i + 4]);
        #pragma unroll
        for (int i = 0; i <= 34; ++i) v[i] = fmaxf(v[i], v[i + 8]);
        #pragma unroll
        for (int i = 0; i <= 18; ++i) v[i] = fmaxf(v[i], v[i + 16]);
        #pragma unroll
        for (int i = 0; i < 16; ++i) s += fabsf(fmaxf(v[i], v[i + 3]));
    }

    // ---- block reduction (deterministic, no atomics) ----
    #pragma unroll
    for (int off = 32; off; off >>= 1) s += __shfl_down(s, off);
    __syncthreads();                      // A4 no longer needed
    float* red = (float*)A4;
    if ((tid & 63) == 0) red[tid >> 6] = s;
    __syncthreads();
    if (tid == 0) part[bid] = red[0] + red[1] + red[2] + red[3];
}

__global__ void dark_reduce(const float* __restrict__ part, float* __restrict__ out, int n) {
    float s = 0.0f;
    for (int i = threadIdx.x; i < n; i += NTHREADS) s += part[i];
    #pragma unroll
    for (int off = 32; off; off >>= 1) s += __shfl_down(s, off);
    __shared__ float w[NTHREADS / 64];
    if ((threadIdx.x & 63) == 0) w[threadIdx.x >> 6] = s;
    __syncthreads();
    if (threadIdx.x == 0) {
        float t = 0.0f;
        #pragma unroll
        for (int i = 0; i < NTHREADS / 64; ++i) t += w[i];
        out[0] = -t * (1.0f / 4194304.0f);   // mean over 16*512*512, negated
    }
}

extern "C" void kernel_launch(void* const* d_in, const int* in_sizes, int n_in,
                              void* d_out, int out_size, void* d_ws, size_t ws_size,
                              hipStream_t stream) {
    const float* x = (const float*)d_in[0];
    float* out  = (float*)d_out;
    float* part = (float*)d_ws;          // 1024 floats = 4 KB

    hipLaunchKernelGGL(dark_main, dim3(1024), dim3(NTHREADS), 0, stream, x, part);
    hipLaunchKernelGGL(dark_reduce, dim3(1), dim3(NTHREADS), 0, stream, part, out, 1024);
}

// Round 2
// 32.111 us; speedup vs baseline: 1.5085x; 1.5085x over previous
//
#include <hip/hip_runtime.h>
#include <math.h>

#define NT 256

// Sliding-35 max via register doubling over w[50] -> 16 outputs (w32 in [0..18])
#define DOUBLE50(w)                                                   \
    _Pragma("unroll") for (int i = 0; i <= 48; ++i) w[i] = fmaxf(w[i], w[i+1]);  \
    _Pragma("unroll") for (int i = 0; i <= 46; ++i) w[i] = fmaxf(w[i], w[i+2]);  \
    _Pragma("unroll") for (int i = 0; i <= 42; ++i) w[i] = fmaxf(w[i], w[i+4]);  \
    _Pragma("unroll") for (int i = 0; i <= 34; ++i) w[i] = fmaxf(w[i], w[i+8]);  \
    _Pragma("unroll") for (int i = 0; i <= 18; ++i) w[i] = fmaxf(w[i], w[i+16]);

__global__ __launch_bounds__(NT, 4)
void dark_main(const float* __restrict__ x, float* __restrict__ part) {
    __shared__ float A[66 * 104];   // region y, stride 104 (f4-aligned rows; col reads conflict-free)
    __shared__ float B[32 * 101];   // vertical max, stride 101 (row reads 2-way = free)
    __shared__ float red[4];        // total LDS = 40400 B -> 4 blocks/CU

    const int tid = threadIdx.x;
    const int bid = blockIdx.x;

    // XCD swizzle: XCD k gets 256 consecutive tiles = 2 whole batches.
    const int swz = (bid & 7) * 256 + (bid >> 3);
    const int b   = swz >> 7;          // 128 tiles per batch (8 tx * 16 tyy)
    const int rem = swz & 127;
    const int tyy = rem >> 3;          // 0..15 (32-row bands)
    const int tx  = rem & 7;           // 0..7  (64-col bands)
    const int h0  = tyy * 32 - 17;
    const int w0c = tx * 64 - 20;      // = w0 - 3, multiple of 4 (f4-aligned)
    const float* xb = x + (size_t)b * 786432u;

    // ---- Phase 0: stage y = 1 - min_c(x) into A[66][104], pad -> 0 ----
    for (int t = tid; t < 66 * 26; t += NT) {
        const int r = t / 26, q = t - r * 26;
        const int gh = h0 + r;
        const bool rv = (unsigned)gh < 512u;
        const int ghc = gh < 0 ? 0 : (gh > 511 ? 511 : gh);
        const float* rowp = xb + ghc * 512;
        const int gw = w0c + 4 * q;
        float4 y;
        if (gw >= 0 && gw <= 508) {                    // whole f4 in-bounds (cols)
            const float4 a = *(const float4*)(rowp + gw);
            const float4 g = *(const float4*)(rowp + gw + 262144);
            const float4 c = *(const float4*)(rowp + gw + 524288);
            y.x = rv ? 1.0f - fminf(a.x, fminf(g.x, c.x)) : 0.0f;
            y.y = rv ? 1.0f - fminf(a.y, fminf(g.y, c.y)) : 0.0f;
            y.z = rv ? 1.0f - fminf(a.z, fminf(g.z, c.z)) : 0.0f;
            y.w = rv ? 1.0f - fminf(a.w, fminf(g.w, c.w)) : 0.0f;
        } else {                                       // image col edges: scalar clamp+mask
            float* ye = (float*)&y;
            #pragma unroll
            for (int e = 0; e < 4; ++e) {
                const int g = gw + e;
                const int gc = g < 0 ? 0 : (g > 511 ? 511 : g);
                const float m = fminf(rowp[gc], fminf(rowp[gc + 262144], rowp[gc + 524288]));
                ye[e] = (rv && (unsigned)g < 512u) ? 1.0f - m : 0.0f;
            }
        }
        *(float4*)&A[r * 104 + 4 * q] = y;
    }
    __syncthreads();

    // ---- Vertical sliding-35 max, registers: 196 tasks x (1 col, 16 out rows) ----
    if (tid < 196) {
        const int chunk = (tid >= 98) ? 1 : 0;
        const int col   = tid - 98 * chunk;
        const float* base = &A[chunk * 16 * 104 + 3 + col];
        float w[50];
        #pragma unroll
        for (int k = 0; k < 50; ++k) w[k] = base[k * 104];
        DOUBLE50(w)
        #pragma unroll
        for (int k = 0; k < 16; ++k)
            B[(chunk * 16 + k) * 101 + col] = fmaxf(w[k], w[k + 3]);
    }
    __syncthreads();

    // ---- Horizontal sliding-35 max + sum: 128 tasks x (1 row, 16 out cols) ----
    float s = 0.0f;
    if (tid < 128) {
        const int r = tid >> 2, j = tid & 3;
        const float* base = &B[r * 101 + 16 * j];
        float w[50];
        #pragma unroll
        for (int k = 0; k < 50; ++k) w[k] = base[k];
        DOUBLE50(w)
        #pragma unroll
        for (int k = 0; k < 16; ++k) s += fabsf(fmaxf(w[k], w[k + 3]));
    }

    // ---- block reduction (deterministic) ----
    #pragma unroll
    for (int off = 32; off; off >>= 1) s += __shfl_down(s, off);
    if ((tid & 63) == 0) red[tid >> 6] = s;
    __syncthreads();
    if (tid == 0) part[bid] = red[0] + red[1] + red[2] + red[3];
}

__global__ void dark_reduce(const float* __restrict__ part, float* __restrict__ out, int n) {
    float s = 0.0f;
    for (int i = threadIdx.x; i < n; i += NT) s += part[i];
    #pragma unroll
    for (int off = 32; off; off >>= 1) s += __shfl_down(s, off);
    __shared__ float w[NT / 64];
    if ((threadIdx.x & 63) == 0) w[threadIdx.x >> 6] = s;
    __syncthreads();
    if (threadIdx.x == 0) {
        float t = 0.0f;
        #pragma unroll
        for (int i = 0; i < NT / 64; ++i) t += w[i];
        out[0] = -t * (1.0f / 4194304.0f);   // -mean over 16*512*512
    }
}

extern "C" void kernel_launch(void* const* d_in, const int* in_sizes, int n_in,
                              void* d_out, int out_size, void* d_ws, size_t ws_size,
                              hipStream_t stream) {
    const float* x = (const float*)d_in[0];
    float* out  = (float*)d_out;
    float* part = (float*)d_ws;          // 2048 floats = 8 KB

    hipLaunchKernelGGL(dark_main, dim3(2048), dim3(NT), 0, stream, x, part);
    hipLaunchKernelGGL(dark_reduce, dim3(1), dim3(NT), 0, stream, part, out, 2048);
}